// Round 1
// baseline (596.816 us; speedup 1.0000x reference)
//
#include <hip/hip_runtime.h>
#include <hip/hip_bf16.h>

#define NN 50000
#define NE 800000
#define DD 128

typedef unsigned int u32;
typedef __attribute__((ext_vector_type(8))) short short8;   // 8 bf16 = 4 VGPRs
typedef __attribute__((ext_vector_type(4))) float f32x4;
typedef __attribute__((ext_vector_type(2))) float f32x2;
typedef __attribute__((ext_vector_type(4))) u32 u32x4;

__device__ __forceinline__ u32 f2bf2(float a, float b){
  union { __hip_bfloat162 h; u32 u; } cv;
  cv.h = __float22bfloat162_rn(make_float2(a, b));   // v_cvt_pk_bf16_f32 on gfx950
  return cv.u;
}
__device__ __forceinline__ f32x2 up2(u32 v){
  f32x2 r;
  r.x = __uint_as_float(v << 16);
  r.y = __uint_as_float(v & 0xffff0000u);
  return r;
}

// ---------------- weight prep: fp32 W -> frag-ordered bf16 (once per launch) ------
// frag (ct,ks) of mat: lane holds W[ct*16+rr][ks*32+quad*8+j], j=0..7 (16 B)
struct PrepArgs { const float* W[6]; u32* out; };
__global__ __launch_bounds__(256) void k_prep(PrepArgs pa){
  int tid = blockIdx.x*256 + threadIdx.x;        // 6 mats * 32 frags * 64 lanes
  int mat = tid >> 11, rem = tid & 2047;
  int frag = rem >> 6, lane = rem & 63;
  int ct = frag >> 2, ks = frag & 3, rr = lane & 15, quad = lane >> 4;
  const float* p = pa.W[mat] + (ct*16 + rr)*128 + ks*32 + quad*8;
  float4 f0 = *(const float4*)p;
  float4 f1 = *(const float4*)(p + 4);
  u32x4 q;
  q.x = f2bf2(f0.x, f0.y); q.y = f2bf2(f0.z, f0.w);
  q.z = f2bf2(f1.x, f1.y); q.w = f2bf2(f1.z, f1.w);
  *(u32x4*)(pa.out + (size_t)tid*4) = q;
}

// ---------------- CSR build ----------------
__global__ void k_hist(const int* __restrict__ dst, int* __restrict__ cnt){
  int i = blockIdx.x*256 + threadIdx.x;
  if (i < NE) atomicAdd(&cnt[dst[i]], 1);
}

// thread-coarsened single-block scan over EVEN-PADDED counts; 2 barriers total.
__global__ __launch_bounds__(1024) void k_scan(const int* __restrict__ cnt,
                                               int* __restrict__ row_start,
                                               int* __restrict__ cursor){
  __shared__ int wsum[16];
  const int t = threadIdx.x, lane = t & 63, wid = t >> 6;
  const int beg = t*49;
  const int end = min(beg + 49, NN);
  int s = 0;
  for (int i = beg; i < end; ++i) s += (cnt[i] + 1) & ~1;
  int incl = s;
  #pragma unroll
  for (int off = 1; off < 64; off <<= 1){
    int u = __shfl_up(incl, off, 64);
    if (lane >= off) incl += u;
  }
  if (lane == 63) wsum[wid] = incl;
  __syncthreads();
  if (wid == 0){
    int w = (lane < 16) ? wsum[lane] : 0;
    #pragma unroll
    for (int off = 1; off < 16; off <<= 1){
      int u = __shfl_up(w, off, 64);
      if (lane >= off) w += u;
    }
    if (lane < 16) wsum[lane] = w;
  }
  __syncthreads();
  int excl = ((wid > 0) ? wsum[wid-1] : 0) + (incl - s);
  for (int i = beg; i < end; ++i){
    row_start[i] = excl;
    cursor[i]    = excl;
    excl += (cnt[i] + 1) & ~1;
  }
  if (t == 0) row_start[NN] = wsum[15];
}

// writes pre-scaled dword offsets: (src+1)*192 (row 0 of H is the zero row;
// pad slots stay 0 from the esrc memset and therefore gather zeros).
__global__ void k_scatter(const int* __restrict__ src, const int* __restrict__ dst,
                          int* __restrict__ cursor, int* __restrict__ esrc){
  int i = blockIdx.x*256 + threadIdx.x;
  if (i < NE){
    int d = dst[i];
    int p = atomicAdd(&cursor[d], 1);
    esrc[p] = (src[i] + 1) * 192;
  }
}

// ------------- fused pre-transform + bf16-MFMA GEMM, barrier-free streaming -------
// W (frag-packed bf16) in 32 KB LDS per block; each wave loads its own 16 A-rows
// straight into MFMA B-frag registers; grid-stride over 3125 groups per manifold.
// H layout: interleaved, row (node+1) = H + (node+1)*192 dw, manifold m at +m*64 dw.
struct GemmArgs {
  const float* A[3];
  const float* Bias[3];
  const u32* Wf;          // frag-packed weights for this layer (3 mats)
  u32* H;
  const float* curv;
  int astride;
};

__global__ __launch_bounds__(256,3) void k_gemm(GemmArgs ga){
  const int m = blockIdx.y;
  const float* __restrict__ A    = ga.A[m];
  const float* __restrict__ Bias = ga.Bias[m];
  u32* __restrict__ H = ga.H;
  const int astride = ga.astride;
  const int t = threadIdx.x;
  const int lane = t & 63;
  const int rr = lane & 15, quad = lane >> 4;

  __shared__ u32 Wlds[8192];        // 32 frags x 64 lanes x 16 B, conflict-free b128
  {
    const u32x4* wsrc = (const u32x4*)(ga.Wf + (size_t)m*8192);
    #pragma unroll
    for (int it = 0; it < 8; ++it){
      int idx = it*256 + t;
      *(u32x4*)&Wlds[idx*4] = wsrc[idx];
    }
  }
  __syncthreads();                  // the only barrier in the kernel

  float sc = 1.f;
  if (m == 1) sc = sqrtf(*ga.curv);

  const int nw = gridDim.x * 4;
  for (int g = blockIdx.x*4 + (t >> 6); g < 3125; g += nw){
    // ---- load 16 rows into B-frag layout: lane(rr,quad) = row rr, k quad*8.. ----
    const float* ap = A + (size_t)(g*16 + rr)*astride + quad*8;
    float4 c[8];
    #pragma unroll
    for (int ks = 0; ks < 4; ++ks){
      c[2*ks]   = *(const float4*)(ap + ks*32);
      c[2*ks+1] = *(const float4*)(ap + ks*32 + 4);
    }
    // ---- row-norm pre-transform (register shuffles, no LDS) ----
    if (m != 0){
      float p = 0.f;
      #pragma unroll
      for (int i = 0; i < 8; ++i)
        p += c[i].x*c[i].x + c[i].y*c[i].y + c[i].z*c[i].z + c[i].w*c[i].w;
      p += __shfl_xor(p, 16, 64);
      p += __shfl_xor(p, 32, 64);
      float nrm = sqrtf(p);
      float sca;
      if (m == 1){    // log-map at origin: (2/sc)*artanh(sc*|y|)/|y|
        float x = sc * nrm;
        sca = (nrm > 1e-30f) ? (logf((1.f + x)/(1.f - x)) / (sc * nrm)) : 2.f;
      } else {        // l2norm
        sca = 1.f / fmaxf(nrm, 1e-12f);
      }
      #pragma unroll
      for (int i = 0; i < 8; ++i){ c[i].x*=sca; c[i].y*=sca; c[i].z*=sca; c[i].w*=sca; }
    }
    // ---- pack to bf16 frags + MFMA (W a-frags re-read from LDS) ----
    f32x4 acc[8];
    #pragma unroll
    for (int ct = 0; ct < 8; ++ct){ f32x4 z = {0.f,0.f,0.f,0.f}; acc[ct] = z; }
    #pragma unroll
    for (int ks = 0; ks < 4; ++ks){
      u32x4 bq;
      bq.x = f2bf2(c[2*ks].x,   c[2*ks].y);
      bq.y = f2bf2(c[2*ks].z,   c[2*ks].w);
      bq.z = f2bf2(c[2*ks+1].x, c[2*ks+1].y);
      bq.w = f2bf2(c[2*ks+1].z, c[2*ks+1].w);
      short8 bf = __builtin_bit_cast(short8, bq);
      #pragma unroll
      for (int ct = 0; ct < 8; ++ct){
        short8 wf = *(const short8*)&Wlds[((ct*4 + ks)*64 + lane)*4];
        acc[ct] = __builtin_amdgcn_mfma_f32_16x16x32_bf16(wf, bf, acc[ct], 0, 0, 0);
      }
    }
    // ---- epilogue: bias (+ spherical l2norm), bf16 pack, store ----
    #pragma unroll
    for (int ct = 0; ct < 8; ++ct){
      float4 bv = *(const float4*)(Bias + ct*16 + quad*4);
      acc[ct].x += bv.x; acc[ct].y += bv.y; acc[ct].z += bv.z; acc[ct].w += bv.w;
    }
    if (m == 2){
      float p = 0.f;
      #pragma unroll
      for (int ct = 0; ct < 8; ++ct)
        p += acc[ct].x*acc[ct].x + acc[ct].y*acc[ct].y + acc[ct].z*acc[ct].z + acc[ct].w*acc[ct].w;
      p += __shfl_xor(p, 16, 64);
      p += __shfl_xor(p, 32, 64);
      float inv = 1.f / fmaxf(sqrtf(p), 1e-12f);
      #pragma unroll
      for (int ct = 0; ct < 8; ++ct){ acc[ct].x*=inv; acc[ct].y*=inv; acc[ct].z*=inv; acc[ct].w*=inv; }
    }
    // channel = ct*16 + quad*4 + reg
    u32* hp = H + (size_t)(g*16 + rr + 1)*192 + m*64 + quad*2;
    #pragma unroll
    for (int ct = 0; ct < 8; ++ct){
      uint2 pk;
      pk.x = f2bf2(acc[ct].x, acc[ct].y);
      pk.y = f2bf2(acc[ct].z, acc[ct].w);
      *(uint2*)(hp + ct*8) = pk;
    }
  }
}

// ------- mean-aggregate + post-transform; one wave per node, 2 edges per pass -----
// lanes 0-31 handle even pair-edge, 32-63 odd; each lane owns 4 features (8 B).
// edge lists are even-padded; pad entries gather the zero row -> no in-loop masking.
struct AggArgs {
  const u32* H;
  float* O;
  const int* row_start;
  const int* cnt;         // real (unpadded) degrees for the mean
  const int* esrc;        // pre-scaled dword offsets (src+1)*192
  const float* curv;
};

__global__ __launch_bounds__(256) void k_agg(AggArgs aa){
  const int tid = threadIdx.x;
  const int lane = tid & 63;
  const int half = lane >> 5, hl = lane & 31;
  const int node = blockIdx.x*4 + (tid >> 6);
  if (node >= NN) return;
  const int e0 = aa.row_start[node], e1 = aa.row_start[node+1];
  const int* __restrict__ esrc = aa.esrc;
  const u32* __restrict__ Hf = aa.H + hl*2;   // lane's 8-byte feature slot

  f32x2 z2 = {0.f, 0.f};
  f32x2 a0[2] = {z2, z2};
  f32x2 a1[2] = {z2, z2};
  f32x2 a2[2] = {z2, z2};

  for (int base = e0; base < e1; base += 64){
    int nn = e1 - base; if (nn > 64) nn = 64;     // always even
    int sv = esrc[min(base + lane, e1 - 1)];      // 64 offsets, one coalesced load
    int np = nn >> 1;
    int p = 0;
    for (; p + 4 <= np; p += 4){                  // 8 edges, 12 dwordx2 gathers in flight
      uint2 q[4][3];
      #pragma unroll
      for (int u = 0; u < 4; ++u){
        int soff = __shfl(sv, 2*(p + u) + half, 64);
        const u32* hp = Hf + soff;
        q[u][0] = *(const uint2*)hp;
        q[u][1] = *(const uint2*)(hp + 64);       // offset:256
        q[u][2] = *(const uint2*)(hp + 128);      // offset:512
      }
      #pragma unroll
      for (int u = 0; u < 4; ++u){
        a0[0] += up2(q[u][0].x); a0[1] += up2(q[u][0].y);
        a1[0] += up2(q[u][1].x); a1[1] += up2(q[u][1].y);
        a2[0] += up2(q[u][2].x); a2[1] += up2(q[u][2].y);
      }
    }
    for (; p < np; ++p){
      int soff = __shfl(sv, 2*p + half, 64);
      const u32* hp = Hf + soff;
      uint2 q0 = *(const uint2*)hp;
      uint2 q1 = *(const uint2*)(hp + 64);
      uint2 q2 = *(const uint2*)(hp + 128);
      a0[0] += up2(q0.x); a0[1] += up2(q0.y);
      a1[0] += up2(q1.x); a1[1] += up2(q1.y);
      a2[0] += up2(q2.x); a2[1] += up2(q2.y);
    }
  }

  // combine the two half-wave edge partitions
  #pragma unroll
  for (int j = 0; j < 2; ++j){
    a0[j].x += __shfl_xor(a0[j].x, 32, 64); a0[j].y += __shfl_xor(a0[j].y, 32, 64);
    a1[j].x += __shfl_xor(a1[j].x, 32, 64); a1[j].y += __shfl_xor(a1[j].y, 32, 64);
    a2[j].x += __shfl_xor(a2[j].x, 32, 64); a2[j].y += __shfl_xor(a2[j].y, 32, 64);
  }
  float inv = 1.f / (float)max(aa.cnt[node], 1);
  #pragma unroll
  for (int j = 0; j < 2; ++j){ a0[j] *= inv; a1[j] *= inv; a2[j] *= inv; }

  float p1 = a1[0].x*a1[0].x + a1[0].y*a1[0].y + a1[1].x*a1[1].x + a1[1].y*a1[1].y;
  float p2 = a2[0].x*a2[0].x + a2[0].y*a2[0].y + a2[1].x*a2[1].x + a2[1].y*a2[1].y;
  #pragma unroll
  for (int off = 1; off < 32; off <<= 1){
    p1 += __shfl_xor(p1, off, 64);
    p2 += __shfl_xor(p2, off, 64);
  }
  float n1 = sqrtf(p1);
  float scv = sqrtf(*aa.curv);
  float x = scv * n1;
  float s1 = (n1 > 1e-30f) ? (tanhf(0.5f*x) / x) : 0.5f;   // exp-map at origin
  float s2 = 1.f / fmaxf(sqrtf(p2), 1e-12f);               // l2norm

  float* op = aa.O + (size_t)node*384;
  if (half == 0){
    float4 e4 = make_float4(a0[0].x > 0.f ? a0[0].x : 0.2f*a0[0].x,
                            a0[0].y > 0.f ? a0[0].y : 0.2f*a0[0].y,
                            a0[1].x > 0.f ? a0[1].x : 0.2f*a0[1].x,
                            a0[1].y > 0.f ? a0[1].y : 0.2f*a0[1].y);
    *(float4*)(op + hl*4) = e4;
    *(float4*)(op + 128 + hl*4) = make_float4(a1[0].x*s1, a1[0].y*s1, a1[1].x*s1, a1[1].y*s1);
  } else {
    *(float4*)(op + 256 + hl*4) = make_float4(a2[0].x*s2, a2[0].y*s2, a2[1].x*s2, a2[1].y*s2);
  }
}

extern "C" void kernel_launch(void* const* d_in, const int* in_sizes, int n_in,
                              void* d_out, int out_size, void* d_ws, size_t ws_size,
                              hipStream_t stream){
  (void)in_sizes; (void)n_in; (void)out_size; (void)ws_size;
  const int*   src    = (const int*)  d_in[0];
  const int*   dst    = (const int*)  d_in[1];
  const float* e_emb  = (const float*)d_in[2];
  const float* b_emb  = (const float*)d_in[3];
  const float* s_emb  = (const float*)d_in[4];
  const float* e_W    = (const float*)d_in[5];
  const float* e_b    = (const float*)d_in[6];
  const float* b_W    = (const float*)d_in[7];
  const float* b_b    = (const float*)d_in[8];
  const float* s_W    = (const float*)d_in[9];
  const float* s_b    = (const float*)d_in[10];
  const float* b_curv = (const float*)d_in[11];
  float* out = (float*)d_out;

  char* ws = (char*)d_ws;
  size_t off = 0;
  auto alloc = [&](size_t bytes) -> void* {
    void* p = (void*)(ws + off);
    off += (bytes + 255) & ~(size_t)255;
    return p;
  };
  int* cnt       = (int*)alloc((size_t)NN*4);
  int* row_start = (int*)alloc((size_t)(NN+1)*4);
  int* cursor    = (int*)alloc((size_t)NN*4);
  int* esrc      = (int*)alloc((size_t)(NE + NN + 64)*4);     // even-padded capacity
  u32* h         = (u32*)alloc((size_t)(NN+1)*192*4);         // row 0 = zero row
  u32* wf        = (u32*)alloc((size_t)6*2048*16);            // frag-packed bf16 weights

  (void)hipMemsetAsync(cnt, 0, (size_t)NN*4, stream);
  (void)hipMemsetAsync(esrc, 0, (size_t)(NE + NN + 64)*4, stream);  // pads -> zero row
  (void)hipMemsetAsync(h, 0, 768, stream);                          // the zero row

  PrepArgs pp;
  pp.W[0] = e_W;          pp.W[1] = b_W;          pp.W[2] = s_W;
  pp.W[3] = e_W + 16384;  pp.W[4] = b_W + 16384;  pp.W[5] = s_W + 16384;
  pp.out = wf;
  k_prep   <<<48, 256, 0, stream>>>(pp);

  k_hist   <<<NE/256, 256, 0, stream>>>(dst, cnt);
  k_scan   <<<1, 1024, 0, stream>>>(cnt, row_start, cursor);
  k_scatter<<<NE/256, 256, 0, stream>>>(src, dst, cursor, esrc);

  GemmArgs g;
  g.H = h; g.curv = b_curv;
  AggArgs a;
  a.H = h; a.O = out; a.row_start = row_start; a.cnt = cnt; a.esrc = esrc; a.curv = b_curv;

  dim3 ggrid(157, 3);          // 628 waves per manifold
  int agrid = (NN + 3)/4;

  // ----- layer 0 -----
  g.astride = DD;
  g.A[0]=e_emb; g.A[1]=b_emb; g.A[2]=s_emb;
  g.Bias[0]=e_b; g.Bias[1]=b_b; g.Bias[2]=s_b;
  g.Wf = wf;
  k_gemm<<<ggrid, 256, 0, stream>>>(g);
  k_agg <<<agrid, 256, 0, stream>>>(a);

  // ----- layer 1 (reads d_out strided, overwrites d_out) -----
  g.astride = 3*DD;
  g.A[0]=out; g.A[1]=out+DD; g.A[2]=out+2*DD;
  g.Bias[0]=e_b+DD; g.Bias[1]=b_b+DD; g.Bias[2]=s_b+DD;
  g.Wf = wf + 3*8192;
  k_gemm<<<ggrid, 256, 0, stream>>>(g);
  k_agg <<<agrid, 256, 0, stream>>>(a);
}

// Round 2
// 496.717 us; speedup vs baseline: 1.2015x; 1.2015x over previous
//
#include <hip/hip_runtime.h>
#include <hip/hip_bf16.h>

#define NN 50000
#define NE 800000
#define DD 128

typedef unsigned int u32;
typedef __attribute__((ext_vector_type(8))) short short8;   // 8 bf16 = 4 VGPRs
typedef __attribute__((ext_vector_type(4))) float f32x4;
typedef __attribute__((ext_vector_type(2))) float f32x2;
typedef __attribute__((ext_vector_type(4))) u32 u32x4;

__device__ __forceinline__ u32 f2bf2(float a, float b){
  union { __hip_bfloat162 h; u32 u; } cv;
  cv.h = __float22bfloat162_rn(make_float2(a, b));   // v_cvt_pk_bf16_f32 on gfx950
  return cv.u;
}
__device__ __forceinline__ f32x2 up2(u32 v){
  f32x2 r;
  r.x = __uint_as_float(v << 16);
  r.y = __uint_as_float(v & 0xffff0000u);
  return r;
}

// ---------------- weight prep: fp32 W -> frag-ordered bf16 (once per launch) ------
// frag (ct,ks) of mat: lane holds W[ct*16+rr][ks*32+quad*8+j], j=0..7 (16 B)
struct PrepArgs { const float* W[6]; u32* out; };
__global__ __launch_bounds__(256) void k_prep(PrepArgs pa){
  int tid = blockIdx.x*256 + threadIdx.x;        // 6 mats * 32 frags * 64 lanes
  int mat = tid >> 11, rem = tid & 2047;
  int frag = rem >> 6, lane = rem & 63;
  int ct = frag >> 2, ks = frag & 3, rr = lane & 15, quad = lane >> 4;
  const float* p = pa.W[mat] + (ct*16 + rr)*128 + ks*32 + quad*8;
  float4 f0 = *(const float4*)p;
  float4 f1 = *(const float4*)(p + 4);
  u32x4 q;
  q.x = f2bf2(f0.x, f0.y); q.y = f2bf2(f0.z, f0.w);
  q.z = f2bf2(f1.x, f1.y); q.w = f2bf2(f1.z, f1.w);
  *(u32x4*)(pa.out + (size_t)tid*4) = q;
}

// ---------------- CSR build ----------------
__global__ void k_hist(const int* __restrict__ dst, int* __restrict__ cnt){
  int i = blockIdx.x*256 + threadIdx.x;
  if (i < NE) atomicAdd(&cnt[dst[i]], 1);
}

// segment bump-allocator: per-wave prefix over padded degrees + one atomic/wave.
// segments need not be ordered -- k_agg only needs disjoint slabs of esrc.
__global__ __launch_bounds__(256) void k_alloc(const int* __restrict__ cnt,
                                               int* __restrict__ row_beg,
                                               int* __restrict__ cursor,
                                               int* __restrict__ gcount){
  int i = blockIdx.x*256 + threadIdx.x;
  int lane = threadIdx.x & 63;
  int pc = (i < NN) ? ((cnt[i] + 1) & ~1) : 0;   // even-padded degree
  int incl = pc;
  #pragma unroll
  for (int off = 1; off < 64; off <<= 1){
    int u = __shfl_up(incl, off, 64);
    if (lane >= off) incl += u;
  }
  int wtot = __shfl(incl, 63, 64);
  int base = 0;
  if (lane == 0) base = atomicAdd(gcount, wtot);
  base = __shfl(base, 0, 64);
  int excl = base + incl - pc;
  if (i < NN){ row_beg[i] = excl; cursor[i] = excl; }
}

// writes pre-scaled dword offsets: (src+1)*192 (row 0 of H is the zero row;
// pad slots stay 0 from the esrc memset and therefore gather zeros).
__global__ void k_scatter(const int* __restrict__ src, const int* __restrict__ dst,
                          int* __restrict__ cursor, int* __restrict__ esrc){
  int i = blockIdx.x*256 + threadIdx.x;
  if (i < NE){
    int d = dst[i];
    int p = atomicAdd(&cursor[d], 1);
    esrc[p] = (src[i] + 1) * 192;
  }
}

// ------------- fused pre-transform + bf16-MFMA GEMM, barrier-free streaming -------
// W (frag-packed bf16) in 32 KB LDS per block; each wave loads its own 16 A-rows
// straight into MFMA B-frag registers; grid-stride over 3125 groups per manifold.
// H layout: interleaved, row (node+1) = H + (node+1)*192 dw, manifold m at +m*64 dw.
struct GemmArgs {
  const float* A[3];
  const float* Bias[3];
  const u32* Wf;          // frag-packed weights for this layer (3 mats)
  u32* H;
  const float* curv;
  int astride;
};

__global__ __launch_bounds__(256,3) void k_gemm(GemmArgs ga){
  const int m = blockIdx.y;
  const float* __restrict__ A    = ga.A[m];
  const float* __restrict__ Bias = ga.Bias[m];
  u32* __restrict__ H = ga.H;
  const int astride = ga.astride;
  const int t = threadIdx.x;
  const int lane = t & 63;
  const int rr = lane & 15, quad = lane >> 4;

  __shared__ u32 Wlds[8192];        // 32 frags x 64 lanes x 16 B, conflict-free b128
  {
    const u32x4* wsrc = (const u32x4*)(ga.Wf + (size_t)m*8192);
    #pragma unroll
    for (int it = 0; it < 8; ++it){
      int idx = it*256 + t;
      *(u32x4*)&Wlds[idx*4] = wsrc[idx];
    }
  }
  __syncthreads();                  // the only barrier in the kernel

  float sc = 1.f;
  if (m == 1) sc = sqrtf(*ga.curv);

  const int nw = gridDim.x * 4;
  for (int g = blockIdx.x*4 + (t >> 6); g < 3125; g += nw){
    // ---- load 16 rows into B-frag layout: lane(rr,quad) = row rr, k quad*8.. ----
    const float* ap = A + (size_t)(g*16 + rr)*astride + quad*8;
    float4 c[8];
    #pragma unroll
    for (int ks = 0; ks < 4; ++ks){
      c[2*ks]   = *(const float4*)(ap + ks*32);
      c[2*ks+1] = *(const float4*)(ap + ks*32 + 4);
    }
    // ---- row-norm pre-transform (register shuffles, no LDS) ----
    if (m != 0){
      float p = 0.f;
      #pragma unroll
      for (int i = 0; i < 8; ++i)
        p += c[i].x*c[i].x + c[i].y*c[i].y + c[i].z*c[i].z + c[i].w*c[i].w;
      p += __shfl_xor(p, 16, 64);
      p += __shfl_xor(p, 32, 64);
      float nrm = sqrtf(p);
      float sca;
      if (m == 1){    // log-map at origin: (2/sc)*artanh(sc*|y|)/|y|
        float x = sc * nrm;
        sca = (nrm > 1e-30f) ? (logf((1.f + x)/(1.f - x)) / (sc * nrm)) : 2.f;
      } else {        // l2norm
        sca = 1.f / fmaxf(nrm, 1e-12f);
      }
      #pragma unroll
      for (int i = 0; i < 8; ++i){ c[i].x*=sca; c[i].y*=sca; c[i].z*=sca; c[i].w*=sca; }
    }
    // ---- pack to bf16 frags + MFMA (W a-frags re-read from LDS) ----
    f32x4 acc[8];
    #pragma unroll
    for (int ct = 0; ct < 8; ++ct){ f32x4 z = {0.f,0.f,0.f,0.f}; acc[ct] = z; }
    #pragma unroll
    for (int ks = 0; ks < 4; ++ks){
      u32x4 bq;
      bq.x = f2bf2(c[2*ks].x,   c[2*ks].y);
      bq.y = f2bf2(c[2*ks].z,   c[2*ks].w);
      bq.z = f2bf2(c[2*ks+1].x, c[2*ks+1].y);
      bq.w = f2bf2(c[2*ks+1].z, c[2*ks+1].w);
      short8 bf = __builtin_bit_cast(short8, bq);
      #pragma unroll
      for (int ct = 0; ct < 8; ++ct){
        short8 wf = *(const short8*)&Wlds[((ct*4 + ks)*64 + lane)*4];
        acc[ct] = __builtin_amdgcn_mfma_f32_16x16x32_bf16(wf, bf, acc[ct], 0, 0, 0);
      }
    }
    // ---- epilogue: bias (+ spherical l2norm), bf16 pack, store ----
    #pragma unroll
    for (int ct = 0; ct < 8; ++ct){
      float4 bv = *(const float4*)(Bias + ct*16 + quad*4);
      acc[ct].x += bv.x; acc[ct].y += bv.y; acc[ct].z += bv.z; acc[ct].w += bv.w;
    }
    if (m == 2){
      float p = 0.f;
      #pragma unroll
      for (int ct = 0; ct < 8; ++ct)
        p += acc[ct].x*acc[ct].x + acc[ct].y*acc[ct].y + acc[ct].z*acc[ct].z + acc[ct].w*acc[ct].w;
      p += __shfl_xor(p, 16, 64);
      p += __shfl_xor(p, 32, 64);
      float inv = 1.f / fmaxf(sqrtf(p), 1e-12f);
      #pragma unroll
      for (int ct = 0; ct < 8; ++ct){ acc[ct].x*=inv; acc[ct].y*=inv; acc[ct].z*=inv; acc[ct].w*=inv; }
    }
    // channel = ct*16 + quad*4 + reg
    u32* hp = H + (size_t)(g*16 + rr + 1)*192 + m*64 + quad*2;
    #pragma unroll
    for (int ct = 0; ct < 8; ++ct){
      uint2 pk;
      pk.x = f2bf2(acc[ct].x, acc[ct].y);
      pk.y = f2bf2(acc[ct].z, acc[ct].w);
      *(uint2*)(hp + ct*8) = pk;
    }
  }
}

// ------- mean-aggregate + post-transform; one wave per node, 2 edges per pass -----
// lanes 0-31 handle even pair-edge, 32-63 odd; each lane owns 4 features (8 B).
// edge lists are even-padded; pad entries gather the zero row -> no in-loop masking.
struct AggArgs {
  const u32* H;
  float* O;
  const int* row_beg;
  const int* cnt;         // real (unpadded) degrees for the mean + segment length
  const int* esrc;        // pre-scaled dword offsets (src+1)*192
  const float* curv;
};

__global__ __launch_bounds__(256) void k_agg(AggArgs aa){
  const int tid = threadIdx.x;
  const int lane = tid & 63;
  const int half = lane >> 5, hl = lane & 31;
  const int node = blockIdx.x*4 + (tid >> 6);
  if (node >= NN) return;
  const int deg = aa.cnt[node];
  const int e0 = aa.row_beg[node];
  const int e1 = e0 + ((deg + 1) & ~1);
  const int* __restrict__ esrc = aa.esrc;
  const u32* __restrict__ Hf = aa.H + hl*2;   // lane's 8-byte feature slot

  f32x2 z2 = {0.f, 0.f};
  f32x2 a0[2] = {z2, z2};
  f32x2 a1[2] = {z2, z2};
  f32x2 a2[2] = {z2, z2};

  for (int base = e0; base < e1; base += 64){
    int nn = e1 - base; if (nn > 64) nn = 64;     // always even
    int sv = esrc[min(base + lane, e1 - 1)];      // 64 offsets, one coalesced load
    int np = nn >> 1;
    int p = 0;
    for (; p + 4 <= np; p += 4){                  // 8 edges, 12 dwordx2 gathers in flight
      uint2 q[4][3];
      #pragma unroll
      for (int u = 0; u < 4; ++u){
        int soff = __shfl(sv, 2*(p + u) + half, 64);
        const u32* hp = Hf + soff;
        q[u][0] = *(const uint2*)hp;
        q[u][1] = *(const uint2*)(hp + 64);       // offset:256
        q[u][2] = *(const uint2*)(hp + 128);      // offset:512
      }
      #pragma unroll
      for (int u = 0; u < 4; ++u){
        a0[0] += up2(q[u][0].x); a0[1] += up2(q[u][0].y);
        a1[0] += up2(q[u][1].x); a1[1] += up2(q[u][1].y);
        a2[0] += up2(q[u][2].x); a2[1] += up2(q[u][2].y);
      }
    }
    for (; p < np; ++p){
      int soff = __shfl(sv, 2*p + half, 64);
      const u32* hp = Hf + soff;
      uint2 q0 = *(const uint2*)hp;
      uint2 q1 = *(const uint2*)(hp + 64);
      uint2 q2 = *(const uint2*)(hp + 128);
      a0[0] += up2(q0.x); a0[1] += up2(q0.y);
      a1[0] += up2(q1.x); a1[1] += up2(q1.y);
      a2[0] += up2(q2.x); a2[1] += up2(q2.y);
    }
  }

  // combine the two half-wave edge partitions
  #pragma unroll
  for (int j = 0; j < 2; ++j){
    a0[j].x += __shfl_xor(a0[j].x, 32, 64); a0[j].y += __shfl_xor(a0[j].y, 32, 64);
    a1[j].x += __shfl_xor(a1[j].x, 32, 64); a1[j].y += __shfl_xor(a1[j].y, 32, 64);
    a2[j].x += __shfl_xor(a2[j].x, 32, 64); a2[j].y += __shfl_xor(a2[j].y, 32, 64);
  }
  float inv = 1.f / (float)max(deg, 1);
  #pragma unroll
  for (int j = 0; j < 2; ++j){ a0[j] *= inv; a1[j] *= inv; a2[j] *= inv; }

  float p1 = a1[0].x*a1[0].x + a1[0].y*a1[0].y + a1[1].x*a1[1].x + a1[1].y*a1[1].y;
  float p2 = a2[0].x*a2[0].x + a2[0].y*a2[0].y + a2[1].x*a2[1].x + a2[1].y*a2[1].y;
  #pragma unroll
  for (int off = 1; off < 32; off <<= 1){
    p1 += __shfl_xor(p1, off, 64);
    p2 += __shfl_xor(p2, off, 64);
  }
  float n1 = sqrtf(p1);
  float scv = sqrtf(*aa.curv);
  float x = scv * n1;
  float s1 = (n1 > 1e-30f) ? (tanhf(0.5f*x) / x) : 0.5f;   // exp-map at origin
  float s2 = 1.f / fmaxf(sqrtf(p2), 1e-12f);               // l2norm

  float* op = aa.O + (size_t)node*384;
  if (half == 0){
    float4 e4 = make_float4(a0[0].x > 0.f ? a0[0].x : 0.2f*a0[0].x,
                            a0[0].y > 0.f ? a0[0].y : 0.2f*a0[0].y,
                            a0[1].x > 0.f ? a0[1].x : 0.2f*a0[1].x,
                            a0[1].y > 0.f ? a0[1].y : 0.2f*a0[1].y);
    *(float4*)(op + hl*4) = e4;
    *(float4*)(op + 128 + hl*4) = make_float4(a1[0].x*s1, a1[0].y*s1, a1[1].x*s1, a1[1].y*s1);
  } else {
    *(float4*)(op + 256 + hl*4) = make_float4(a2[0].x*s2, a2[0].y*s2, a2[1].x*s2, a2[1].y*s2);
  }
}

extern "C" void kernel_launch(void* const* d_in, const int* in_sizes, int n_in,
                              void* d_out, int out_size, void* d_ws, size_t ws_size,
                              hipStream_t stream){
  (void)in_sizes; (void)n_in; (void)out_size; (void)ws_size;
  const int*   src    = (const int*)  d_in[0];
  const int*   dst    = (const int*)  d_in[1];
  const float* e_emb  = (const float*)d_in[2];
  const float* b_emb  = (const float*)d_in[3];
  const float* s_emb  = (const float*)d_in[4];
  const float* e_W    = (const float*)d_in[5];
  const float* e_b    = (const float*)d_in[6];
  const float* b_W    = (const float*)d_in[7];
  const float* b_b    = (const float*)d_in[8];
  const float* s_W    = (const float*)d_in[9];
  const float* s_b    = (const float*)d_in[10];
  const float* b_curv = (const float*)d_in[11];
  float* out = (float*)d_out;

  char* ws = (char*)d_ws;
  size_t off = 0;
  auto alloc = [&](size_t bytes) -> void* {
    void* p = (void*)(ws + off);
    off += (bytes + 255) & ~(size_t)255;
    return p;
  };
  int* cnt       = (int*)alloc((size_t)NN*4);
  int* row_beg   = (int*)alloc((size_t)NN*4);
  int* cursor    = (int*)alloc((size_t)NN*4);
  int* gcount    = (int*)alloc(256);
  int* esrc      = (int*)alloc((size_t)(NE + NN + 64)*4);     // even-padded capacity
  u32* h         = (u32*)alloc((size_t)(NN+1)*192*4);         // row 0 = zero row
  u32* wf        = (u32*)alloc((size_t)6*2048*16);            // frag-packed bf16 weights

  (void)hipMemsetAsync(cnt, 0, (size_t)NN*4, stream);
  (void)hipMemsetAsync(gcount, 0, 4, stream);
  (void)hipMemsetAsync(esrc, 0, (size_t)(NE + NN + 64)*4, stream);  // pads -> zero row
  (void)hipMemsetAsync(h, 0, 768, stream);                          // the zero row

  PrepArgs pp;
  pp.W[0] = e_W;          pp.W[1] = b_W;          pp.W[2] = s_W;
  pp.W[3] = e_W + 16384;  pp.W[4] = b_W + 16384;  pp.W[5] = s_W + 16384;
  pp.out = wf;
  k_prep   <<<48, 256, 0, stream>>>(pp);

  k_hist   <<<NE/256, 256, 0, stream>>>(dst, cnt);
  k_alloc  <<<(NN+255)/256, 256, 0, stream>>>(cnt, row_beg, cursor, gcount);
  k_scatter<<<NE/256, 256, 0, stream>>>(src, dst, cursor, esrc);

  GemmArgs g;
  g.H = h; g.curv = b_curv;
  AggArgs a;
  a.H = h; a.O = out; a.row_beg = row_beg; a.cnt = cnt; a.esrc = esrc; a.curv = b_curv;

  dim3 ggrid(157, 3);          // 628 waves per manifold
  int agrid = (NN + 3)/4;

  // ----- layer 0 -----
  g.astride = DD;
  g.A[0]=e_emb; g.A[1]=b_emb; g.A[2]=s_emb;
  g.Bias[0]=e_b; g.Bias[1]=b_b; g.Bias[2]=s_b;
  g.Wf = wf;
  k_gemm<<<ggrid, 256, 0, stream>>>(g);
  k_agg <<<agrid, 256, 0, stream>>>(a);

  // ----- layer 1 (reads d_out strided, overwrites d_out) -----
  g.astride = 3*DD;
  g.A[0]=out; g.A[1]=out+DD; g.A[2]=out+2*DD;
  g.Bias[0]=e_b+DD; g.Bias[1]=b_b+DD; g.Bias[2]=s_b+DD;
  g.Wf = wf + 3*8192;
  k_gemm<<<ggrid, 256, 0, stream>>>(g);
  k_agg <<<agrid, 256, 0, stream>>>(a);
}